// Round 10
// baseline (481.371 us; speedup 1.0000x reference)
//
#include <hip/hip_runtime.h>
#include <hip/hip_bf16.h>
#include <stdint.h>

// Router GEMM: out[8192,768] (fp32) = X[8192,6144] @ W[768,6144]^T
// Device buffers hold FP32 upcasts of the bf16 data (round-6 discovery).
// Round 10: round-8 proven skeleton (2-barrier, 1-step reg prefetch) +
//   - SPLITK 2->4: grid 1536 = 6 blocks/CU = 24 waves/CU (TLP x2; r7->r8
//     proved TLP converts ~directly to time here)
//   - corrected bank swizzle slot = k8 ^ ((row>>1)&3) (r9: conflicts -> 0)
//   - __launch_bounds__(256,6) to admit 6 blocks/CU
// r9 lesson kept OUT: no issue-before-compute reordering (it degenerated the
// ds_write's vmcnt wait to ~0-distance and serialized the loop).

#define M_DIM 8192
#define N_DIM 768
#define K_DIM 6144

#define BM 128
#define BN 128
#define BK 32
#define SPLITK 4
#define KSEG (K_DIM / SPLITK)    // 1536 per block
#define NT (KSEG / BK)           // 48 K-steps

typedef __bf16 bf16x8 __attribute__((ext_vector_type(8)));
typedef float f32x4 __attribute__((ext_vector_type(4)));

static __device__ __forceinline__ __bf16 bf16_trunc(float f) {
    uint32_t u = __builtin_bit_cast(uint32_t, f);
    return __builtin_bit_cast(__bf16, (uint16_t)(u >> 16));  // exact on upcast data
}

static __device__ __forceinline__ bf16x8 pack_bf16x8(f32x4 a, f32x4 b) {
    bf16x8 r;
    #pragma unroll
    for (int j = 0; j < 4; ++j) {
        r[j]     = bf16_trunc(a[j]);
        r[4 + j] = bf16_trunc(b[j]);
    }
    return r;
}

__global__ __launch_bounds__(256, 6) void router_gemm_sk4_kernel(
    const float* __restrict__ X, const float* __restrict__ W,
    float* __restrict__ out)
{
    __shared__ __align__(16) __bf16 As[BM * BK];   // 8 KiB
    __shared__ __align__(16) __bf16 Bs[BN * BK];   // 8 KiB

    const int tid  = threadIdx.x;
    const int w    = tid >> 6;
    const int lane = tid & 63;

    // XCD decode: blockIdx round-robins across 8 XCDs; XCD x owns
    // {bmi 0..7} x {bn 0..5} x {ks 0..3}; bm = x*8+bmi -> X panels XCD-local.
    const int xcd  = blockIdx.x & 7;
    const int slot = blockIdx.x >> 3;      // 0..191
    const int bmi  = slot & 7;
    const int tt   = slot >> 3;            // 0..23
    const int bn   = tt % 6;
    const int ks   = tt / 6;               // 0..3
    const int bm   = xcd * 8 + bmi;        // 0..63

    const int kbase = ks * KSEG;

    const int wr = w >> 1;                 // wave row 0..1 (64 m-rows)
    const int wc = w & 1;                  // wave col 0..1 (64 n-cols)

    const int lrow = lane & 15;
    const int kg   = lane >> 4;

    // staging: unit u in [0,512) per tile; row=u>>2, k8=u&3 (8 bf16 per unit)
    const int srow = tid >> 2;             // 0..63 (also writes srow+64)
    const int sk8  = tid & 3;              // logical k-slot 0..3
    // conflict-free swizzle (r9-verified): physical slot = k8 ^ ((row>>1)&3)
    const int wslot0 = (sk8 ^ ((srow >> 1) & 3)) * 8;

    const float* Xg = X + (size_t)(bm * BM) * K_DIM;
    const float* Wg = W + (size_t)(bn * BN) * K_DIM;
    const float* xrow0 = Xg + (size_t)srow * K_DIM + sk8 * 8;
    const float* xrow1 = xrow0 + (size_t)64 * K_DIM;
    const float* wrow0 = Wg + (size_t)srow * K_DIM + sk8 * 8;
    const float* wrow1 = wrow0 + (size_t)64 * K_DIM;

    f32x4 pr[8];

    #define ISSUE_LOADS(K0)                                  \
        do {                                                 \
            pr[0] = *(const f32x4*)(xrow0 + (K0));           \
            pr[1] = *(const f32x4*)(xrow0 + (K0) + 4);       \
            pr[2] = *(const f32x4*)(xrow1 + (K0));           \
            pr[3] = *(const f32x4*)(xrow1 + (K0) + 4);       \
            pr[4] = *(const f32x4*)(wrow0 + (K0));           \
            pr[5] = *(const f32x4*)(wrow0 + (K0) + 4);       \
            pr[6] = *(const f32x4*)(wrow1 + (K0));           \
            pr[7] = *(const f32x4*)(wrow1 + (K0) + 4);       \
        } while (0)

    #define WRITE_LDS()                                                         \
        do {                                                                    \
            *(bf16x8*)(As + srow * BK + wslot0)        = pack_bf16x8(pr[0], pr[1]); \
            *(bf16x8*)(As + (srow + 64) * BK + wslot0) = pack_bf16x8(pr[2], pr[3]); \
            *(bf16x8*)(Bs + srow * BK + wslot0)        = pack_bf16x8(pr[4], pr[5]); \
            *(bf16x8*)(Bs + (srow + 64) * BK + wslot0) = pack_bf16x8(pr[6], pr[7]); \
        } while (0)

    ISSUE_LOADS(kbase);
    WRITE_LDS();
    __syncthreads();

    f32x4 acc[4][4] = {};

    // frag read: physical slot = kg ^ ((row>>1)&3), row = base + f*16 + lrow
    const int rslot = (kg ^ ((lrow >> 1) & 3)) * 8;
    const int arow0 = wr * 64 + lrow;
    const int brow0 = wc * 64 + lrow;

    for (int t = 0; t < NT; ++t) {
        if (t + 1 < NT) ISSUE_LOADS(kbase + (t + 1) * BK);

        bf16x8 a[4], b[4];
        #pragma unroll
        for (int mf = 0; mf < 4; ++mf)
            a[mf] = *(const bf16x8*)(As + (arow0 + mf * 16) * BK + rslot);
        #pragma unroll
        for (int nf = 0; nf < 4; ++nf)
            b[nf] = *(const bf16x8*)(Bs + (brow0 + nf * 16) * BK + rslot);

        #pragma unroll
        for (int mf = 0; mf < 4; ++mf)
            #pragma unroll
            for (int nf = 0; nf < 4; ++nf)
                acc[mf][nf] = __builtin_amdgcn_mfma_f32_16x16x32_bf16(
                    a[mf], b[nf], acc[mf][nf], 0, 0, 0);

        __syncthreads();
        if (t + 1 < NT) WRITE_LDS();
        __syncthreads();
    }

    // epilogue: relaxed device-scope fp32 atomic add (out zeroed in launch).
    const int orow0 = bm * BM + wr * 64 + kg * 4;
    const int ocol0 = bn * BN + wc * 64 + lrow;
    #pragma unroll
    for (int mf = 0; mf < 4; ++mf)
        #pragma unroll
        for (int nf = 0; nf < 4; ++nf)
            #pragma unroll
            for (int r = 0; r < 4; ++r) {
                float* o = out + (size_t)(orow0 + mf * 16 + r) * N_DIM
                               + (ocol0 + nf * 16);
                __hip_atomic_fetch_add(o, acc[mf][nf][r],
                                       __ATOMIC_RELAXED, __HIP_MEMORY_SCOPE_AGENT);
            }

    #undef ISSUE_LOADS
    #undef WRITE_LDS
}

extern "C" void kernel_launch(void* const* d_in, const int* in_sizes, int n_in,
                              void* d_out, int out_size, void* d_ws, size_t ws_size,
                              hipStream_t stream) {
    const float* X;
    const float* W;
    if (in_sizes[0] == M_DIM * K_DIM) {
        X = (const float*)d_in[0];
        W = (const float*)d_in[1];
    } else {
        X = (const float*)d_in[1];
        W = (const float*)d_in[0];
    }
    float* out = (float*)d_out;

    // zero-init for atomic accumulation (async stream op: graph-capture-safe)
    hipMemsetAsync(out, 0, (size_t)M_DIM * N_DIM * sizeof(float), stream);

    const int grid = (M_DIM / BM) * (N_DIM / BN) * SPLITK;   // 64*6*4 = 1536
    hipLaunchKernelGGL(router_gemm_sk4_kernel, dim3(grid), dim3(256), 0, stream,
                       X, W, out);
}

// Round 11
// 175.332 us; speedup vs baseline: 2.7455x; 2.7455x over previous
//
#include <hip/hip_runtime.h>
#include <hip/hip_bf16.h>
#include <stdint.h>

// Router GEMM: out[8192,768] (fp32) = X[8192,6144] @ W[768,6144]^T
// Device buffers hold FP32 upcasts of the bf16 data (round-6 discovery).
// Round 11: register-pressure-aware TLP scaling.
//   r9/r10 lesson: forcing occupancy via launch_bounds spills acc -> scratch
//   (945MB scratch traffic in r10). Instead SHRINK per-thread state:
//   512 threads / 8 waves, wave-tile 64x32 -> acc[4][2]=32 AGPR, pr[4]=16,
//   frags 24 -> ~92 unified regs < 128 budget at (512,4). 2 blocks/CU
//   resident = 16 waves/CU (r8 measured ~10).
//   Kept from r8: 2-barrier skeleton, 1-step reg prefetch, SK grid, XCD-local
//   X panels, r9-verified conflict-free swizzle slot=k8^((row>>1)&3), atomics.

#define M_DIM 8192
#define N_DIM 768
#define K_DIM 6144

#define BM 128
#define BN 128
#define BK 32
#define SPLITK 4
#define KSEG (K_DIM / SPLITK)    // 1536 per block
#define NT (KSEG / BK)           // 48 K-steps

typedef __bf16 bf16x8 __attribute__((ext_vector_type(8)));
typedef float f32x4 __attribute__((ext_vector_type(4)));

static __device__ __forceinline__ __bf16 bf16_trunc(float f) {
    uint32_t u = __builtin_bit_cast(uint32_t, f);
    return __builtin_bit_cast(__bf16, (uint16_t)(u >> 16));  // exact on upcast data
}

static __device__ __forceinline__ bf16x8 pack_bf16x8(f32x4 a, f32x4 b) {
    bf16x8 r;
    #pragma unroll
    for (int j = 0; j < 4; ++j) {
        r[j]     = bf16_trunc(a[j]);
        r[4 + j] = bf16_trunc(b[j]);
    }
    return r;
}

__global__ __launch_bounds__(512, 4) void router_gemm_w8_kernel(
    const float* __restrict__ X, const float* __restrict__ W,
    float* __restrict__ out)
{
    __shared__ __align__(16) __bf16 As[BM * BK];   // 8 KiB
    __shared__ __align__(16) __bf16 Bs[BN * BK];   // 8 KiB

    const int tid  = threadIdx.x;
    const int w    = tid >> 6;             // wave 0..7
    const int lane = tid & 63;

    // XCD decode: blockIdx round-robins across 8 XCDs; XCD x owns
    // {bmi 0..7} x {bn 0..5} x {ks 0..3}; bm = x*8+bmi -> X panels XCD-local.
    const int xcd  = blockIdx.x & 7;
    const int slot = blockIdx.x >> 3;      // 0..191
    const int bmi  = slot & 7;
    const int tt   = slot >> 3;            // 0..23
    const int bn   = tt % 6;
    const int ks   = tt / 6;               // 0..3
    const int bm   = xcd * 8 + bmi;        // 0..63

    const int kbase = ks * KSEG;

    const int wr = w >> 2;                 // wave row 0..1 (64 m-rows)
    const int wc = w & 3;                  // wave col 0..3 (32 n-cols)

    const int lrow = lane & 15;
    const int kg   = lane >> 4;

    // staging: 512 threads, each moves one A-unit and one B-unit (8 elems).
    // unit tid: row = tid>>2 (0..127), k8 = tid&3.
    const int srow = tid >> 2;
    const int sk8  = tid & 3;
    // conflict-free swizzle (r9-verified): physical slot = k8 ^ ((row>>1)&3)
    const int wslot0 = (sk8 ^ ((srow >> 1) & 3)) * 8;

    const float* Xg = X + (size_t)(bm * BM) * K_DIM;
    const float* Wg = W + (size_t)(bn * BN) * K_DIM;
    const float* xrow = Xg + (size_t)srow * K_DIM + sk8 * 8;
    const float* wrow = Wg + (size_t)srow * K_DIM + sk8 * 8;

    f32x4 pr[4];

    #define ISSUE_LOADS(K0)                          \
        do {                                         \
            pr[0] = *(const f32x4*)(xrow + (K0));    \
            pr[1] = *(const f32x4*)(xrow + (K0) + 4);\
            pr[2] = *(const f32x4*)(wrow + (K0));    \
            pr[3] = *(const f32x4*)(wrow + (K0) + 4);\
        } while (0)

    #define WRITE_LDS()                                                       \
        do {                                                                  \
            *(bf16x8*)(As + srow * BK + wslot0) = pack_bf16x8(pr[0], pr[1]);  \
            *(bf16x8*)(Bs + srow * BK + wslot0) = pack_bf16x8(pr[2], pr[3]);  \
        } while (0)

    ISSUE_LOADS(kbase);
    WRITE_LDS();
    __syncthreads();

    f32x4 acc[4][2] = {};

    // frag read: physical slot = kg ^ ((row>>1)&3); row-base offsets are
    // multiples of 16 so (row>>1)&3 == (lrow>>1)&3 for all fragments.
    const int rslot = (kg ^ ((lrow >> 1) & 3)) * 8;
    const int arow0 = wr * 64 + lrow;      // + mf*16
    const int brow0 = wc * 32 + lrow;      // + nf*16

    for (int t = 0; t < NT; ++t) {
        if (t + 1 < NT) ISSUE_LOADS(kbase + (t + 1) * BK);

        bf16x8 a[4], b[2];
        #pragma unroll
        for (int mf = 0; mf < 4; ++mf)
            a[mf] = *(const bf16x8*)(As + (arow0 + mf * 16) * BK + rslot);
        #pragma unroll
        for (int nf = 0; nf < 2; ++nf)
            b[nf] = *(const bf16x8*)(Bs + (brow0 + nf * 16) * BK + rslot);

        #pragma unroll
        for (int mf = 0; mf < 4; ++mf)
            #pragma unroll
            for (int nf = 0; nf < 2; ++nf)
                acc[mf][nf] = __builtin_amdgcn_mfma_f32_16x16x32_bf16(
                    a[mf], b[nf], acc[mf][nf], 0, 0, 0);

        __syncthreads();
        if (t + 1 < NT) WRITE_LDS();
        __syncthreads();
    }

    // epilogue: relaxed device-scope fp32 atomic add (out zeroed in launch).
    // C/D layout col = lane&15, row = (lane>>4)*4 + reg (verified).
    const int orow0 = bm * BM + wr * 64 + kg * 4;
    const int ocol0 = bn * BN + wc * 32 + lrow;
    #pragma unroll
    for (int mf = 0; mf < 4; ++mf)
        #pragma unroll
        for (int nf = 0; nf < 2; ++nf)
            #pragma unroll
            for (int r = 0; r < 4; ++r) {
                float* o = out + (size_t)(orow0 + mf * 16 + r) * N_DIM
                               + (ocol0 + nf * 16);
                __hip_atomic_fetch_add(o, acc[mf][nf][r],
                                       __ATOMIC_RELAXED, __HIP_MEMORY_SCOPE_AGENT);
            }

    #undef ISSUE_LOADS
    #undef WRITE_LDS
}

extern "C" void kernel_launch(void* const* d_in, const int* in_sizes, int n_in,
                              void* d_out, int out_size, void* d_ws, size_t ws_size,
                              hipStream_t stream) {
    const float* X;
    const float* W;
    if (in_sizes[0] == M_DIM * K_DIM) {
        X = (const float*)d_in[0];
        W = (const float*)d_in[1];
    } else {
        X = (const float*)d_in[1];
        W = (const float*)d_in[0];
    }
    float* out = (float*)d_out;

    // zero-init for atomic accumulation (async stream op: graph-capture-safe)
    hipMemsetAsync(out, 0, (size_t)M_DIM * N_DIM * sizeof(float), stream);

    const int grid = (M_DIM / BM) * (N_DIM / BN) * SPLITK;   // 64*6*4 = 1536
    hipLaunchKernelGGL(router_gemm_w8_kernel, dim3(grid), dim3(512), 0, stream,
                       X, W, out);
}